// Round 5
// baseline (659.339 us; speedup 1.0000x reference)
//
#include <hip/hip_runtime.h>

// Reference reduces to: y = circular_depthwise_conv16(x, w) / 64;
//   h = y + x;  out = ln_w * (h - mean_H(h)) / sqrt(var_H(h) + 1e-12) + ln_b
// (ortho rfft * ortho rfft -> ortho irfft nets a 1/sqrt(S) = 1/64 scale.)
//
// R5: TLP instead of compiler-fought prefetch. R3/R4: allocator pins 64 VGPR
// and folds loads into uses (vmcnt stalls, ~50% duty/wave); with only
// 4 waves/SIMD (grid 4096 waves) that left HBM at 30%. CHUNK=32 doubles the
// grid to 8192 waves = 8 waves/SIMD (the max at 64 VGPR, forced via
// __launch_bounds__(256,8)) -> stalls overlap across waves. Halo becomes
// +50% of reads but is L3-resident (R4: FETCH 81MB < 134MB input).

constexpr int S = 4096;
constexpr int H = 128;
constexpr int K = 16;
constexpr int CHUNK = 32;   // seq rows per wave
constexpr int G = 8;        // rows per compute group / load batch

typedef float v2f __attribute__((ext_vector_type(2)));

// x + dpp_perm(x); disabled/invalid lanes contribute 0 (old=0, bound_ctrl=1)
template <int CTRL, int ROWMASK>
__device__ __forceinline__ float dpp_add(float x) {
    int y = __builtin_amdgcn_update_dpp(0, __float_as_int(x), CTRL, ROWMASK, 0xf, true);
    return x + __int_as_float(y);
}

// Sum over 64 lanes, broadcast to all lanes. 6 full-rate VALU adds + readlane.
__device__ __forceinline__ float wave_sum(float x) {
    x = dpp_add<0x111, 0xf>(x);  // row_shr:1
    x = dpp_add<0x112, 0xf>(x);  // row_shr:2
    x = dpp_add<0x114, 0xf>(x);  // row_shr:4
    x = dpp_add<0x118, 0xf>(x);  // row_shr:8  -> lane 15/31/47/63 = row sums
    x = dpp_add<0x142, 0xa>(x);  // row_bcast15 -> rows 1,3
    x = dpp_add<0x143, 0xc>(x);  // row_bcast31 -> rows 2,3; lane 63 = total
    return __int_as_float(__builtin_amdgcn_readlane(__float_as_int(x), 63));
}

__global__ __launch_bounds__(256, 8)
void fconv_ln_kernel(const float* __restrict__ x,      // [B,S,H]
                     const float* __restrict__ wconv,  // [K,H]
                     const float* __restrict__ lnw,    // [H]
                     const float* __restrict__ lnb,    // [H]
                     float* __restrict__ out)          // [B,S,H]
{
    const int wid  = (blockIdx.x * blockDim.x + threadIdx.x) >> 6;
    const int lane = threadIdx.x & 63;

    const int chunksPerSeq = S / CHUNK;            // 128
    const int b  = wid / chunksPerSeq;
    const int t0 = (wid % chunksPerSeq) * CHUNK;

    const int c2 = lane * 2;                       // this lane's channel pair

    float2 w[K];
#pragma unroll
    for (int k = 0; k < K; ++k)
        w[k] = *reinterpret_cast<const float2*>(&wconv[k * H + c2]);

    const float2 gamma = *reinterpret_cast<const float2*>(&lnw[c2]);
    const float2 beta  = *reinterpret_cast<const float2*>(&lnb[c2]);

    const float* xb = x   + (size_t)b * S * H;
    float*       ob = out + (size_t)b * S * H;

    float2 hist[K];    // rows (groupStart-16 .. groupStart-1)
    float2 cur[G];     // rows (groupStart .. groupStart+G-1)
    float2 nxt[G];     // next group (issued early; compiler may fold)

    // preamble: history (circular wrap) + group 0
#pragma unroll
    for (int s = 0; s < K; ++s) {
        int t = (t0 - K + s + S) & (S - 1);
        hist[s] = *reinterpret_cast<const float2*>(&xb[(size_t)t * H + c2]);
    }
#pragma unroll
    for (int j = 0; j < G; ++j)
        cur[j] = *reinterpret_cast<const float2*>(&xb[(size_t)(t0 + j) * H + c2]);

    for (int tb = 0; tb < CHUNK; tb += G) {
        // issue next group's loads before compute (latency hiding within wave)
        if (tb + G < CHUNK) {
#pragma unroll
            for (int j = 0; j < G; ++j)
                nxt[j] = *reinterpret_cast<const float2*>(
                    &xb[(size_t)(t0 + tb + G + j) * H + c2]);
        }

#pragma unroll
        for (int j = 0; j < G; ++j) {
            // x[t-k]: k<=j -> cur[j-k]; k>j -> hist[K + j - k]   (static idx)
            float ax = 0.f, ay = 0.f;
#pragma unroll
            for (int k = 0; k < K; ++k) {
                const float2 v = (k <= j) ? cur[j - k] : hist[K + j - k];
                ax = fmaf(w[k].x, v.x, ax);
                ay = fmaf(w[k].y, v.y, ay);
            }
            const float2 xt = cur[j];
            float hx = fmaf(ax, 0.015625f, xt.x);   // conv/64 + residual
            float hy = fmaf(ay, 0.015625f, xt.y);

            // LayerNorm over H=128: two DPP allreduces (VALU pipe)
            const float s1 = wave_sum(hx + hy);
            const float s2 = wave_sum(hx * hx + hy * hy);
            const float u   = s1 * (1.0f / H);
            const float var = fmaf(s2, 1.0f / H, -u * u);
            const float inv = rsqrtf(var + 1e-12f);

            v2f o;
            o.x = fmaf(gamma.x * inv, hx - u, beta.x);
            o.y = fmaf(gamma.y * inv, hy - u, beta.y);
            // non-temporal: output is never re-read; don't evict L3 input
            __builtin_nontemporal_store(
                o, reinterpret_cast<v2f*>(&ob[(size_t)(t0 + tb + j) * H + c2]));
        }

        // slide window: hist <- {hist[G..], cur}; cur <- nxt   (static copies)
#pragma unroll
        for (int s = 0; s < K - G; ++s) hist[s] = hist[s + G];
#pragma unroll
        for (int j = 0; j < G; ++j)     hist[K - G + j] = cur[j];
#pragma unroll
        for (int j = 0; j < G; ++j)     cur[j] = nxt[j];
    }
}

extern "C" void kernel_launch(void* const* d_in, const int* in_sizes, int n_in,
                              void* d_out, int out_size, void* d_ws, size_t ws_size,
                              hipStream_t stream)
{
    const float* x     = (const float*)d_in[0];   // [64,4096,128]
    const float* wconv = (const float*)d_in[1];   // [1,16,128]
    const float* lnw   = (const float*)d_in[2];   // [128]
    const float* lnb   = (const float*)d_in[3];   // [128]
    float*       out   = (float*)d_out;

    const int Bsz = in_sizes[0] / (S * H);        // 64
    const int totalWaves = Bsz * (S / CHUNK);     // 8192
    const int threads = 256;
    const int blocks  = totalWaves * 64 / threads; // 2048

    hipLaunchKernelGGL(fconv_ln_kernel, dim3(blocks), dim3(threads), 0, stream,
                       x, wconv, lnw, lnb, out);
}

// Round 9
// 242.108 us; speedup vs baseline: 2.7233x; 2.7233x over previous
//
#include <hip/hip_runtime.h>

// Reference reduces to: y = circular_depthwise_conv16(x, w) / 64;
//   h = y + x;  out = ln_w * (h - mean_H(h)) / sqrt(var_H(h) + 1e-12) + ln_b
// (ortho rfft * ortho rfft -> ortho irfft nets a 1/sqrt(S) = 1/64 scale.)
//
// R6: CHUNK=32 for 8192 waves (8 waves/SIMD at 64 VGPR) with the PROVEN
// launch_bounds(256,4) config (R3/R4: allocator chose 64 VGPR, no spill).
// R5's (256,8) clamped to 32 VGPR and spilled ~1.6GB to scratch (516us).
// Latency hiding comes from TLP (8 resident waves), not from fighting the
// allocator for an in-register prefetch.

constexpr int S = 4096;
constexpr int H = 128;
constexpr int K = 16;
constexpr int CHUNK = 32;   // seq rows per wave -> 8192 waves = 8/SIMD
constexpr int G = 8;        // rows per compute group / load batch

typedef float v2f __attribute__((ext_vector_type(2)));

// x + dpp_perm(x); disabled/invalid lanes contribute 0 (old=0, bound_ctrl=1)
template <int CTRL, int ROWMASK>
__device__ __forceinline__ float dpp_add(float x) {
    int y = __builtin_amdgcn_update_dpp(0, __float_as_int(x), CTRL, ROWMASK, 0xf, true);
    return x + __int_as_float(y);
}

// Sum over 64 lanes, broadcast to all lanes. 6 full-rate VALU adds + readlane.
__device__ __forceinline__ float wave_sum(float x) {
    x = dpp_add<0x111, 0xf>(x);  // row_shr:1
    x = dpp_add<0x112, 0xf>(x);  // row_shr:2
    x = dpp_add<0x114, 0xf>(x);  // row_shr:4
    x = dpp_add<0x118, 0xf>(x);  // row_shr:8  -> lane 15/31/47/63 = row sums
    x = dpp_add<0x142, 0xa>(x);  // row_bcast15 -> rows 1,3
    x = dpp_add<0x143, 0xc>(x);  // row_bcast31 -> rows 2,3; lane 63 = total
    return __int_as_float(__builtin_amdgcn_readlane(__float_as_int(x), 63));
}

__global__ __launch_bounds__(256, 4)
void fconv_ln_kernel(const float* __restrict__ x,      // [B,S,H]
                     const float* __restrict__ wconv,  // [K,H]
                     const float* __restrict__ lnw,    // [H]
                     const float* __restrict__ lnb,    // [H]
                     float* __restrict__ out)          // [B,S,H]
{
    const int wid  = (blockIdx.x * blockDim.x + threadIdx.x) >> 6;
    const int lane = threadIdx.x & 63;

    const int chunksPerSeq = S / CHUNK;            // 128
    const int b  = wid / chunksPerSeq;
    const int t0 = (wid % chunksPerSeq) * CHUNK;

    const int c2 = lane * 2;                       // this lane's channel pair

    float2 w[K];
#pragma unroll
    for (int k = 0; k < K; ++k)
        w[k] = *reinterpret_cast<const float2*>(&wconv[k * H + c2]);

    const float2 gamma = *reinterpret_cast<const float2*>(&lnw[c2]);
    const float2 beta  = *reinterpret_cast<const float2*>(&lnb[c2]);

    const float* xb = x   + (size_t)b * S * H;
    float*       ob = out + (size_t)b * S * H;

    float2 hist[K];    // rows (groupStart-16 .. groupStart-1)
    float2 cur[G];     // rows (groupStart .. groupStart+G-1)
    float2 nxt[G];     // next group (issued early; TLP covers if folded)

    // preamble: history (circular wrap) + group 0
#pragma unroll
    for (int s = 0; s < K; ++s) {
        int t = (t0 - K + s + S) & (S - 1);
        hist[s] = *reinterpret_cast<const float2*>(&xb[(size_t)t * H + c2]);
    }
#pragma unroll
    for (int j = 0; j < G; ++j)
        cur[j] = *reinterpret_cast<const float2*>(&xb[(size_t)(t0 + j) * H + c2]);

    for (int tb = 0; tb < CHUNK; tb += G) {
        // issue next group's loads before compute (latency hiding within wave)
        if (tb + G < CHUNK) {
#pragma unroll
            for (int j = 0; j < G; ++j)
                nxt[j] = *reinterpret_cast<const float2*>(
                    &xb[(size_t)(t0 + tb + G + j) * H + c2]);
        }

#pragma unroll
        for (int j = 0; j < G; ++j) {
            // x[t-k]: k<=j -> cur[j-k]; k>j -> hist[K + j - k]   (static idx)
            float ax = 0.f, ay = 0.f;
#pragma unroll
            for (int k = 0; k < K; ++k) {
                const float2 v = (k <= j) ? cur[j - k] : hist[K + j - k];
                ax = fmaf(w[k].x, v.x, ax);
                ay = fmaf(w[k].y, v.y, ay);
            }
            const float2 xt = cur[j];
            float hx = fmaf(ax, 0.015625f, xt.x);   // conv/64 + residual
            float hy = fmaf(ay, 0.015625f, xt.y);

            // LayerNorm over H=128: two DPP allreduces (VALU pipe)
            const float s1 = wave_sum(hx + hy);
            const float s2 = wave_sum(hx * hx + hy * hy);
            const float u   = s1 * (1.0f / H);
            const float var = fmaf(s2, 1.0f / H, -u * u);
            const float inv = rsqrtf(var + 1e-12f);

            v2f o;
            o.x = fmaf(gamma.x * inv, hx - u, beta.x);
            o.y = fmaf(gamma.y * inv, hy - u, beta.y);
            // non-temporal: output is never re-read; don't evict L3 input
            __builtin_nontemporal_store(
                o, reinterpret_cast<v2f*>(&ob[(size_t)(t0 + tb + j) * H + c2]));
        }

        // slide window: hist <- {hist[G..], cur}; cur <- nxt   (static copies)
#pragma unroll
        for (int s = 0; s < K - G; ++s) hist[s] = hist[s + G];
#pragma unroll
        for (int j = 0; j < G; ++j)     hist[K - G + j] = cur[j];
#pragma unroll
        for (int j = 0; j < G; ++j)     cur[j] = nxt[j];
    }
}

extern "C" void kernel_launch(void* const* d_in, const int* in_sizes, int n_in,
                              void* d_out, int out_size, void* d_ws, size_t ws_size,
                              hipStream_t stream)
{
    const float* x     = (const float*)d_in[0];   // [64,4096,128]
    const float* wconv = (const float*)d_in[1];   // [1,16,128]
    const float* lnw   = (const float*)d_in[2];   // [128]
    const float* lnb   = (const float*)d_in[3];   // [128]
    float*       out   = (float*)d_out;

    const int Bsz = in_sizes[0] / (S * H);        // 64
    const int totalWaves = Bsz * (S / CHUNK);     // 8192
    const int threads = 256;
    const int blocks  = totalWaves * 64 / threads; // 2048

    hipLaunchKernelGGL(fconv_ln_kernel, dim3(blocks), dim3(threads), 0, stream,
                       x, wconv, lnw, lnb, out);
}

// Round 10
// 240.652 us; speedup vs baseline: 2.7398x; 1.0060x over previous
//
#include <hip/hip_runtime.h>

// Reference reduces to: y = circular_depthwise_conv16(x, w) / 64;
//   h = y + x;  out = ln_w * (h - mean_H(h)) / sqrt(var_H(h) + 1e-12) + ln_b
// (ortho rfft * ortho rfft -> ortho irfft nets a 1/sqrt(S) = 1/64 scale.)
//
// R10: kill the allocator's rematerialization. R4/R9: scheduler targets the
// 8-wave/EU boundary (64 VGPR) and re-loads x at use sites (legal under
// __restrict__) instead of keeping the 96-reg ring live -> serial load->use
// chains, dur invariant to occupancy. Fix: (a) amdgpu_waves_per_eu(4,4) caps
// target occupancy at 4 waves/EU so 128 VGPR is "free"; (b) NO __restrict__,
// so x-reloads can't be sunk past out-stores (possible alias) -> values must
// stay in registers and the early-issued prefetch survives.

constexpr int S = 4096;
constexpr int H = 128;
constexpr int K = 16;
constexpr int CHUNK = 32;   // seq rows per wave -> 8192 waves (2x oversubscribe)
constexpr int G = 8;        // rows per compute group / load batch

typedef float v2f __attribute__((ext_vector_type(2)));

// x + dpp_perm(x); disabled/invalid lanes contribute 0 (old=0, bound_ctrl=1)
template <int CTRL, int ROWMASK>
__device__ __forceinline__ float dpp_add(float x) {
    int y = __builtin_amdgcn_update_dpp(0, __float_as_int(x), CTRL, ROWMASK, 0xf, true);
    return x + __int_as_float(y);
}

// Sum over 64 lanes, broadcast to all lanes. 6 full-rate VALU adds + readlane.
__device__ __forceinline__ float wave_sum(float x) {
    x = dpp_add<0x111, 0xf>(x);  // row_shr:1
    x = dpp_add<0x112, 0xf>(x);  // row_shr:2
    x = dpp_add<0x114, 0xf>(x);  // row_shr:4
    x = dpp_add<0x118, 0xf>(x);  // row_shr:8  -> lane 15/31/47/63 = row sums
    x = dpp_add<0x142, 0xa>(x);  // row_bcast15 -> rows 1,3
    x = dpp_add<0x143, 0xc>(x);  // row_bcast31 -> rows 2,3; lane 63 = total
    return __int_as_float(__builtin_amdgcn_readlane(__float_as_int(x), 63));
}

__global__ __launch_bounds__(256)
__attribute__((amdgpu_waves_per_eu(4, 4)))
void fconv_ln_kernel(const float* x,      // [B,S,H]  (no restrict: forbid remat)
                     const float* wconv,  // [K,H]
                     const float* lnw,    // [H]
                     const float* lnb,    // [H]
                     float* out)          // [B,S,H]
{
    const int wid  = (blockIdx.x * blockDim.x + threadIdx.x) >> 6;
    const int lane = threadIdx.x & 63;

    const int chunksPerSeq = S / CHUNK;            // 128
    const int b  = wid / chunksPerSeq;
    const int t0 = (wid % chunksPerSeq) * CHUNK;

    const int c2 = lane * 2;                       // this lane's channel pair

    float2 w[K];                                   // 32 VGPR, must stay live
#pragma unroll
    for (int k = 0; k < K; ++k)
        w[k] = *reinterpret_cast<const float2*>(&wconv[k * H + c2]);

    const float2 gamma = *reinterpret_cast<const float2*>(&lnw[c2]);
    const float2 beta  = *reinterpret_cast<const float2*>(&lnb[c2]);

    const float* xb = x   + (size_t)b * S * H;
    float*       ob = out + (size_t)b * S * H;

    float2 hist[K];    // rows (groupStart-16 .. groupStart-1)   32 VGPR
    float2 cur[G];     // rows (groupStart .. groupStart+G-1)    16 VGPR
    float2 nxt[G];     // in-flight prefetch of next group       16 VGPR

    // preamble: history (circular wrap) + group 0
#pragma unroll
    for (int s = 0; s < K; ++s) {
        int t = (t0 - K + s + S) & (S - 1);
        hist[s] = *reinterpret_cast<const float2*>(&xb[(size_t)t * H + c2]);
    }
#pragma unroll
    for (int j = 0; j < G; ++j)
        cur[j] = *reinterpret_cast<const float2*>(&xb[(size_t)(t0 + j) * H + c2]);

#pragma unroll
    for (int tb = 0; tb < CHUNK; tb += G) {
        // issue next group's loads before compute; without restrict these
        // cannot be sunk past the stores below -> real in-flight prefetch
        if (tb + G < CHUNK) {
#pragma unroll
            for (int j = 0; j < G; ++j)
                nxt[j] = *reinterpret_cast<const float2*>(
                    &xb[(size_t)(t0 + tb + G + j) * H + c2]);
        }

#pragma unroll
        for (int j = 0; j < G; ++j) {
            // x[t-k]: k<=j -> cur[j-k]; k>j -> hist[K + j - k]   (static idx)
            float ax = 0.f, ay = 0.f;
#pragma unroll
            for (int k = 0; k < K; ++k) {
                const float2 v = (k <= j) ? cur[j - k] : hist[K + j - k];
                ax = fmaf(w[k].x, v.x, ax);
                ay = fmaf(w[k].y, v.y, ay);
            }
            const float2 xt = cur[j];
            float hx = fmaf(ax, 0.015625f, xt.x);   // conv/64 + residual
            float hy = fmaf(ay, 0.015625f, xt.y);

            // LayerNorm over H=128: two DPP allreduces (VALU pipe)
            const float s1 = wave_sum(hx + hy);
            const float s2 = wave_sum(hx * hx + hy * hy);
            const float u   = s1 * (1.0f / H);
            const float var = fmaf(s2, 1.0f / H, -u * u);
            const float inv = rsqrtf(var + 1e-12f);

            v2f o;
            o.x = fmaf(gamma.x * inv, hx - u, beta.x);
            o.y = fmaf(gamma.y * inv, hy - u, beta.y);
            // non-temporal: output is never re-read; don't evict L3 input
            __builtin_nontemporal_store(
                o, reinterpret_cast<v2f*>(&ob[(size_t)(t0 + tb + j) * H + c2]));
        }

        // slide window: hist <- {hist[G..], cur}; cur <- nxt   (static copies)
#pragma unroll
        for (int s = 0; s < K - G; ++s) hist[s] = hist[s + G];
#pragma unroll
        for (int j = 0; j < G; ++j)     hist[K - G + j] = cur[j];
#pragma unroll
        for (int j = 0; j < G; ++j)     cur[j] = nxt[j];
    }
}

extern "C" void kernel_launch(void* const* d_in, const int* in_sizes, int n_in,
                              void* d_out, int out_size, void* d_ws, size_t ws_size,
                              hipStream_t stream)
{
    const float* x     = (const float*)d_in[0];   // [64,4096,128]
    const float* wconv = (const float*)d_in[1];   // [1,16,128]
    const float* lnw   = (const float*)d_in[2];   // [128]
    const float* lnb   = (const float*)d_in[3];   // [128]
    float*       out   = (float*)d_out;

    const int Bsz = in_sizes[0] / (S * H);        // 64
    const int totalWaves = Bsz * (S / CHUNK);     // 8192
    const int threads = 256;
    const int blocks  = totalWaves * 64 / threads; // 2048

    hipLaunchKernelGGL(fconv_ln_kernel, dim3(blocks), dim3(threads), 0, stream,
                       x, wconv, lnw, lnb, out);
}

// Round 11
// 237.766 us; speedup vs baseline: 2.7731x; 1.0121x over previous
//
#include <hip/hip_runtime.h>

// Reference reduces to: y = circular_depthwise_conv16(x, w) / 64;
//   h = y + x;  out = ln_w * (h - mean_H(h)) / sqrt(var_H(h) + 1e-12) + ln_b
// (ortho rfft * ortho rfft -> ortho irfft nets a 1/sqrt(S) = 1/64 scale.)
//
// R11: architectural latency fix. R4-R10 showed the compiler always folds
// register loads into uses (64-VGPR squeeze) -> 1-2 loads in flight/wave ->
// 2.9 TB/s. global_load_lds is fire-and-forget (no VGPR dest, use only after
// explicit barrier) so a 40-issue burst/block CANNOT be serialized: ~160KB
// in flight/CU vs ~15KB needed. LDS tile also drops the allocator's
// occupancy target to 4 waves/EU (40KB/block) -> 128-VGPR budget for free.

constexpr int S = 4096;
constexpr int H = 128;
constexpr int K = 16;
constexpr int TB = 64;            // output rows per block
constexpr int ROWS = TB + K;      // 80 staged rows (16 halo)
constexpr int NCHUNK = ROWS / 2;  // 40 x 1KB staging chunks (2 rows each)

typedef float v2f __attribute__((ext_vector_type(2)));
typedef const void __attribute__((address_space(1))) gas_v;
typedef void __attribute__((address_space(3))) las_v;

__device__ __forceinline__ void async_copy16(const float* gsrc, float* ldst) {
    // lane l's 16B land at (wave-uniform ldst) + l*16; gsrc is per-lane.
    __builtin_amdgcn_global_load_lds((gas_v*)gsrc, (las_v*)ldst, 16, 0, 0);
}

// x + dpp_perm(x); disabled/invalid lanes contribute 0 (old=0, bound_ctrl=1)
template <int CTRL, int ROWMASK>
__device__ __forceinline__ float dpp_add(float x) {
    int y = __builtin_amdgcn_update_dpp(0, __float_as_int(x), CTRL, ROWMASK, 0xf, true);
    return x + __int_as_float(y);
}

// Sum over 64 lanes, broadcast. 6 full-rate VALU adds + readlane.
__device__ __forceinline__ float wave_sum(float x) {
    x = dpp_add<0x111, 0xf>(x);  // row_shr:1
    x = dpp_add<0x112, 0xf>(x);  // row_shr:2
    x = dpp_add<0x114, 0xf>(x);  // row_shr:4
    x = dpp_add<0x118, 0xf>(x);  // row_shr:8
    x = dpp_add<0x142, 0xa>(x);  // row_bcast15
    x = dpp_add<0x143, 0xc>(x);  // row_bcast31 -> lane 63 = total
    return __int_as_float(__builtin_amdgcn_readlane(__float_as_int(x), 63));
}

__global__ __launch_bounds__(256)
void fconv_ln_kernel(const float* __restrict__ x,      // [B,S,H]
                     const float* __restrict__ wconv,  // [K,H]
                     const float* __restrict__ lnw,    // [H]
                     const float* __restrict__ lnb,    // [H]
                     float* __restrict__ out)          // [B,S,H]
{
    __shared__ float tile[ROWS * H];                   // 40 KB

    const int wv   = threadIdx.x >> 6;                 // wave 0..3
    const int lane = threadIdx.x & 63;

    const int chunksPerSeq = S / TB;                   // 64
    const int b  = blockIdx.x / chunksPerSeq;
    const int t0 = (blockIdx.x % chunksPerSeq) * TB;

    const int c2 = lane * 2;                           // this lane's channels

    const float* xb = x   + (size_t)b * S * H;
    float*       ob = out + (size_t)b * S * H;

    // ---- weights / LN params (registers; small, L2/L3-hot) ----
    float2 w[K];
#pragma unroll
    for (int k = 0; k < K; ++k)
        w[k] = *reinterpret_cast<const float2*>(&wconv[k * H + c2]);
    const float2 gamma = *reinterpret_cast<const float2*>(&lnw[c2]);
    const float2 beta  = *reinterpret_cast<const float2*>(&lnb[c2]);

    // ---- stage 80 rows into LDS: 40x1KB fire-and-forget copies ----
    // chunk c covers LDS rows {2c, 2c+1}; lane l -> row 2c+(l>>5), 16B col (l&31)
    {
        const int rsub = lane >> 5;           // row within chunk
        const int coff = (lane & 31) * 4;     // float col offset
#pragma unroll
        for (int i = 0; i < NCHUNK / 4; ++i) {       // 10 chunks per wave
            const int c  = wv * (NCHUNK / 4) + i;
            const int rr = 2 * c + rsub;             // LDS row 0..79
            const int gt = (t0 - K + rr) & (S - 1);  // wrapped global row
            async_copy16(xb + (size_t)gt * H + coff, &tile[c * 256]);
        }
    }
    asm volatile("s_waitcnt vmcnt(0)" ::: "memory");
    __syncthreads();

    // ---- compute: wave wv owns output rows t0+wv*16 .. +15 ----
    // ring[m & 15] holds LDS row (wv*16 + m); taps for output j are
    // rows wv*16+j+1 .. wv*16+j+16 (LDS row o=16+wv*16+j is x[t], tap k = row o-k)
    const int start = wv * 16;
    float2 ring[K];
#pragma unroll
    for (int m = 1; m <= 15; ++m)
        ring[m] = *reinterpret_cast<const float2*>(&tile[(start + m) * H + c2]);

#pragma unroll
    for (int j = 0; j < 16; ++j) {
        ring[j & 15] = *reinterpret_cast<const float2*>(
            &tile[(start + 16 + j) * H + c2]);       // x[t] itself (tap k=0)

        float ax = 0.f, ay = 0.f;
#pragma unroll
        for (int k = 0; k < K; ++k) {
            const float2 v = ring[(j + 16 - k) & 15];
            ax = fmaf(w[k].x, v.x, ax);
            ay = fmaf(w[k].y, v.y, ay);
        }
        const float2 xt = ring[j & 15];
        float hx = fmaf(ax, 0.015625f, xt.x);        // conv/64 + residual
        float hy = fmaf(ay, 0.015625f, xt.y);

        const float s1 = wave_sum(hx + hy);
        const float s2 = wave_sum(hx * hx + hy * hy);
        const float u   = s1 * (1.0f / H);
        const float var = fmaf(s2, 1.0f / H, -u * u);
        const float inv = rsqrtf(var + 1e-12f);

        v2f o;
        o.x = fmaf(gamma.x * inv, hx - u, beta.x);
        o.y = fmaf(gamma.y * inv, hy - u, beta.y);
        __builtin_nontemporal_store(
            o, reinterpret_cast<v2f*>(&ob[(size_t)(t0 + start + j) * H + c2]));
    }
}

extern "C" void kernel_launch(void* const* d_in, const int* in_sizes, int n_in,
                              void* d_out, int out_size, void* d_ws, size_t ws_size,
                              hipStream_t stream)
{
    const float* x     = (const float*)d_in[0];   // [64,4096,128]
    const float* wconv = (const float*)d_in[1];   // [1,16,128]
    const float* lnw   = (const float*)d_in[2];   // [128]
    const float* lnb   = (const float*)d_in[3];   // [128]
    float*       out   = (float*)d_out;

    const int Bsz    = in_sizes[0] / (S * H);     // 64
    const int blocks = Bsz * (S / TB);            // 4096
    hipLaunchKernelGGL(fconv_ln_kernel, dim3(blocks), dim3(256), 0, stream,
                       x, wconv, lnw, lnb, out);
}